// Round 7
// baseline (303.793 us; speedup 1.0000x reference)
//
#include <hip/hip_runtime.h>
#include <hip/hip_bf16.h>

typedef unsigned short u16;
typedef unsigned int u32;
typedef __attribute__((ext_vector_type(8))) __bf16 bfrag;   // MFMA A/B fragment (4 VGPRs)
typedef __attribute__((ext_vector_type(4))) float f32x4;    // MFMA C/D fragment

#define NN 30
#define FF 4
#define EE 870
#define BSZ 32
#define CC 64
#define TT 128
#define NF 120
#define TSTRIDE 15240
#define OUTHALF 487680
#define AST 72            // activation LDS row stride in u16

__device__ __forceinline__ float bf2f(u16 u) {
    union { u32 i; float f; } v; v.i = ((u32)u) << 16; return v.f;
}
__device__ __forceinline__ u16 f2bf(float f) {
    __hip_bfloat16 h = __float2bfloat16(f); return *(u16*)&h;
}
__device__ __forceinline__ float ldv(const void* p, int idx, int isbf) {
    if (isbf) return bf2f(((const u16*)p)[idx]);
    return ((const float*)p)[idx];
}
__device__ __forceinline__ float softplus_clip(float z) {
    float sp = fmaxf(z, 0.f) + log1pf(expf(-fabsf(z)));
    return fminf(fmaxf(sp, 1e-8f), 100.f);
}
__device__ __forceinline__ f32x4 MFMA(bfrag a, bfrag b, f32x4 c) {
    return __builtin_amdgcn_mfma_f32_16x16x32_bf16(a, b, c, 0, 0, 0);
}

// Per-wave inline dtype probe. graph entries are exactly 0.0/1.0.
// bf16 layout: even u16 words hit 0x3F80 whp; fp32 layout: even words
// (low mantissa halves of 0.0/1.0) are always 0x0000.
__device__ __forceinline__ int probe_isbf(const u16* g, int lane) {
    int hit = (g[2 * lane] == 0x3F80u) | (g[128 + 2 * lane] == 0x3F80u);
    unsigned long long b = __ballot(hit);
    return (b != 0ull) ? 1 : 0;
}

// Gather a B-fragment from a row-major KxO(=64) weight matrix:
// frag element j = W[kb+j][o]. 8 strided scalar loads + pack.
// Deliberately expensive-to-rematerialize so the compiler keeps the
// result resident in VGPRs instead of sinking it into the main loop.
__device__ __forceinline__ bfrag load_bfragT(const void* W, int o, int kb, int isbf) {
    union { bfrag f; u16 s[8]; } u;
#pragma unroll
    for (int j = 0; j < 8; j++) {
        u.s[j] = isbf ? ((const u16*)W)[(kb + j) * 64 + o]
                      : f2bf(((const float*)W)[(kb + j) * 64 + o]);
    }
    return u.f;
}
// A-fragment of W3^T (16x64, rows 4..15 zero) from row-major 64x4 W3:
// element j = (m<4) ? W3[kb+j][m] : 0.
__device__ __forceinline__ bfrag load_w3frag(const void* W3, int m, int kb, int isbf) {
    union { bfrag f; u16 s[8]; } u;
#pragma unroll
    for (int j = 0; j < 8; j++) {
        u.s[j] = (m < 4) ? (isbf ? ((const u16*)W3)[(kb + j) * 4 + m]
                                 : f2bf(((const float*)W3)[(kb + j) * 4 + m]))
                         : (u16)0;
    }
    return u.f;
}

__global__ __launch_bounds__(256, 2)
void sim_fused(const void* __restrict__ data,
               const void* __restrict__ graph,
               const void* __restrict__ mW1, const void* __restrict__ mB1,
               const void* __restrict__ mW2, const void* __restrict__ mB2,
               const void* __restrict__ aW1, const void* __restrict__ aB1,
               const void* __restrict__ aW2, const void* __restrict__ aB2,
               const void* __restrict__ aW3, const void* __restrict__ aB3,
               const void* __restrict__ vW1, const void* __restrict__ vB1,
               const void* __restrict__ vW2, const void* __restrict__ vB2,
               const void* __restrict__ vW3, const void* __restrict__ vB3,
               void* __restrict__ out)
{
    __shared__ __align__(16) float xN[NF];
    __shared__ __align__(16) float pJ[NN * 64];
    __shared__ __align__(16) u32 gmaskS[32];
    __shared__ __align__(16) u16 S[32 * AST];
    __shared__ __align__(16) u16 Am[32 * AST];  // agg-mean, later h2-mean (alias safe: same wave, prog order)
    __shared__ __align__(16) u16 Av[32 * AST];  // agg-var,  later h2-var
    __shared__ __align__(16) u16 Hm[32 * AST];
    __shared__ __align__(16) u16 Hv[32 * AST];

    const int tid  = threadIdx.x;
    const int lane = tid & 63;
    const int wv   = tid >> 6;        // 0..3
    const int ln15 = lane & 15;
    const int quad = lane >> 4;
    const int bs   = blockIdx.x >> 6;
    const int c    = blockIdx.x & 63;
    const int isbf = probe_isbf((const u16*)graph, lane);

    const bool isMean = (wv < 2);
    const int rb = wv & 1;            // this wave's 16-row block

    // ---- build edge masks via ballot (replaces prep kernel) ----
#pragma unroll
    for (int t = 0; t < 8; t++) {
        const int i = wv + t * 4;
        if (i < NN) {
            float g = (lane < 29) ? ldv(graph, bs * EE + i * 29 + lane, isbf) : 0.f;
            unsigned long long bal = __ballot(g > 0.5f);
            if (lane == 0) gmaskS[i] = (u32)bal;
        }
    }
    if (tid >= NN && tid < 32) gmaskS[tid] = 0u;

    // ---- stage node features; zero pad rows ----
    if (isbf) {
        if (tid < 60) {
            u32 w = ((const u32*)data)[((bs * TT + 2 * c) * NF) / 2 + tid];
            xN[tid * 2]     = bf2f((u16)(w & 0xFFFF));
            xN[tid * 2 + 1] = bf2f((u16)(w >> 16));
        }
    } else {
        if (tid < NF) xN[tid] = ((const float*)data)[(bs * TT + 2 * c) * NF + tid];
    }
    if (tid < 128) S[(30 + (tid >> 6)) * AST + (tid & 63)] = 0;  // stay zero forever

    // ---- per-lane small weights / biases ----
    float w1r[8];
#pragma unroll
    for (int k = 0; k < 8; k++) w1r[k] = ldv(mW1, k * 64 + lane, isbf);
    const float b1r = ldv(mB1, lane, isbf);

    float b2cb[4], h1b[4], h2b[4], b3r[4];
#pragma unroll
    for (int cb = 0; cb < 4; cb++) {
        b2cb[cb] = ldv(mB2, cb * 16 + ln15, isbf);
        h1b[cb]  = ldv(isMean ? aB1 : vB1, cb * 16 + ln15, isbf);
        h2b[cb]  = ldv(isMean ? aB2 : vB2, cb * 16 + ln15, isbf);
    }
#pragma unroll
    for (int r = 0; r < 4; r++) b3r[r] = ldv(isMean ? aB3 : vB3, r, isbf);

    // ---- gather ALL B-fragments into registers from original weights ----
    const void* H1src = isMean ? aW1 : vW1;
    const void* H2src = isMean ? aW2 : vW2;
    const void* W3src = isMean ? aW3 : vW3;
    bfrag bW2[8], bH1[8], bH2[8];
#pragma unroll
    for (int cb = 0; cb < 4; cb++) {
        const int o = cb * 16 + ln15;
        bW2[2*cb]   = load_bfragT(mW2,  o, quad * 8,      isbf);
        bW2[2*cb+1] = load_bfragT(mW2,  o, 32 + quad * 8, isbf);
        bH1[2*cb]   = load_bfragT(H1src, o, quad * 8,      isbf);
        bH1[2*cb+1] = load_bfragT(H1src, o, 32 + quad * 8, isbf);
        bH2[2*cb]   = load_bfragT(H2src, o, quad * 8,      isbf);
        bH2[2*cb+1] = load_bfragT(H2src, o, 32 + quad * 8, isbf);
    }
    const bfrag e_a0 = load_w3frag(W3src, ln15, quad * 8,      isbf);
    const bfrag e_a1 = load_w3frag(W3src, ln15, 32 + quad * 8, isbf);

    u16* bufA  = isMean ? Am : Av;
    u16* bufH  = isMean ? Hm : Hv;
    u16* bufH2 = isMean ? Am : Av;   // alias of bufA — same-wave program order makes this safe

    __syncthreads();

    // per-row active-edge counts (needs gmaskS complete)
    float ngr[4];
#pragma unroll
    for (int r = 0; r < 4; r++) {
        int row = rb * 16 + quad * 4 + r;
        ngr[r] = (row < NN) ? (float)__popc(gmaskS[row]) : 0.f;
    }

    for (int step = 0; step < 2; step++) {
        // ---- pJ[j][h] = x_j . W1[4:8, h] ----
        for (int i = wv; i < NN; i += 4) {
            float4 xv = *(const float4*)&xN[i * 4];
            pJ[i * 64 + lane] = xv.x * w1r[4] + xv.y * w1r[5] + xv.z * w1r[6] + xv.w * w1r[7];
        }
        __syncthreads();

        // ---- edge accumulation: S[i][h] = sum_{j active} relu(pI + pJ) ----
        for (int i = wv; i < NN; i += 4) {
            float4 xv = *(const float4*)&xN[i * 4];
            float pI = b1r + xv.x * w1r[0] + xv.y * w1r[1] + xv.z * w1r[2] + xv.w * w1r[3];
            u32 gm = __builtin_amdgcn_readfirstlane(gmaskS[i]);
            float s = 0.f;
#pragma unroll
            for (int e = 0; e < 29; e++) {
                if (gm & (1u << e)) {          // wave-uniform branch: skips inactive edges
                    int j = e + (e >= i);
                    s += fmaxf(pI + pJ[j * 64 + lane], 0.f);
                }
            }
            S[i * AST + lane] = f2bf(s);
        }
        __syncthreads();

        // ---- agg = S @ W2 + ng*b2 : each wave does its FULL 16x64 row-block ----
        {
            bfrag a0 = *(const bfrag*)&S[(rb * 16 + ln15) * AST + quad * 8];
            bfrag a1 = *(const bfrag*)&S[(rb * 16 + ln15) * AST + 32 + quad * 8];
#pragma unroll
            for (int cb = 0; cb < 4; cb++) {
                f32x4 acc = {0.f, 0.f, 0.f, 0.f};
                acc = MFMA(a0, bW2[2*cb], acc);
                acc = MFMA(a1, bW2[2*cb+1], acc);
#pragma unroll
                for (int r = 0; r < 4; r++) {
                    int row = rb * 16 + quad * 4 + r;
                    bufA[row * AST + cb * 16 + ln15] = f2bf(acc[r] + ngr[r] * b2cb[cb]);
                }
            }
        }

        // ---- h1 = relu(agg @ W1 + b1) — wave-private, no barrier ----
        {
            bfrag a0 = *(const bfrag*)&bufA[(rb * 16 + ln15) * AST + quad * 8];
            bfrag a1 = *(const bfrag*)&bufA[(rb * 16 + ln15) * AST + 32 + quad * 8];
#pragma unroll
            for (int cb = 0; cb < 4; cb++) {
                f32x4 acc = {0.f, 0.f, 0.f, 0.f};
                acc = MFMA(a0, bH1[2*cb], acc);
                acc = MFMA(a1, bH1[2*cb+1], acc);
#pragma unroll
                for (int r = 0; r < 4; r++) {
                    int row = rb * 16 + quad * 4 + r;
                    bufH[row * AST + cb * 16 + ln15] = f2bf(fmaxf(acc[r] + h1b[cb], 0.f));
                }
            }
        }

        // ---- h2 = relu(h1 @ W2' + b2') — wave-private, no barrier ----
        {
            bfrag a0 = *(const bfrag*)&bufH[(rb * 16 + ln15) * AST + quad * 8];
            bfrag a1 = *(const bfrag*)&bufH[(rb * 16 + ln15) * AST + 32 + quad * 8];
#pragma unroll
            for (int cb = 0; cb < 4; cb++) {
                f32x4 acc = {0.f, 0.f, 0.f, 0.f};
                acc = MFMA(a0, bH2[2*cb], acc);
                acc = MFMA(a1, bH2[2*cb+1], acc);
#pragma unroll
                for (int r = 0; r < 4; r++) {
                    int row = rb * 16 + quad * 4 + r;
                    bufH2[row * AST + cb * 16 + ln15] = f2bf(fmaxf(acc[r] + h2b[cb], 0.f));
                }
            }
        }

        // ---- epilogue: out^T = W3T @ h2^T — wave-private, no barrier ----
        {
            bfrag b0 = *(const bfrag*)&bufH2[(rb * 16 + ln15) * AST + quad * 8];
            bfrag b1 = *(const bfrag*)&bufH2[(rb * 16 + ln15) * AST + 32 + quad * 8];
            f32x4 acc = {0.f, 0.f, 0.f, 0.f};
            acc = MFMA(e_a0, b0, acc);
            acc = MFMA(e_a1, b1, acc);
            const int n = rb * 16 + ln15;
            const int t = 2 * c + step;
            if (quad == 0 && n < NN) {
                float v[4];
#pragma unroll
                for (int r = 0; r < 4; r++) v[r] = acc[r] + b3r[r];
                if (!isMean) {
#pragma unroll
                    for (int r = 0; r < 4; r++) v[r] = softplus_clip(v[r]);
                }
                if (t < 127) {
                    size_t o = (size_t)bs * TSTRIDE + (size_t)t * NF + n * 4
                             + (isMean ? 0 : OUTHALF);
                    if (isbf) {
                        u16* op = (u16*)out;
                        u32 lo = (u32)f2bf(v[0]) | ((u32)f2bf(v[1]) << 16);
                        u32 hi = (u32)f2bf(v[2]) | ((u32)f2bf(v[3]) << 16);
                        *(u32*)&op[o] = lo;
                        *(u32*)&op[o + 2] = hi;
                    } else {
                        float* op = (float*)out;
                        op[o] = v[0]; op[o+1] = v[1]; op[o+2] = v[2]; op[o+3] = v[3];
                    }
                }
                if (isMean && step == 0) {
                    xN[n*4]   = v[0]; xN[n*4+1] = v[1];
                    xN[n*4+2] = v[2]; xN[n*4+3] = v[3];
                }
            }
        }
        __syncthreads();   // xN/pJ/S step boundary
    }
}

extern "C" void kernel_launch(void* const* d_in, const int* in_sizes, int n_in,
                              void* d_out, int out_size, void* d_ws, size_t ws_size,
                              hipStream_t stream) {
    (void)in_sizes; (void)n_in; (void)out_size; (void)d_ws; (void)ws_size;

    const void* data  = d_in[0];
    const void* graph = d_in[1];

    sim_fused<<<BSZ * CC, 256, 0, stream>>>(data, graph,
        d_in[2], d_in[3], d_in[4], d_in[5],
        d_in[6], d_in[7], d_in[8], d_in[9], d_in[10], d_in[11],
        d_in[12], d_in[13], d_in[14], d_in[15], d_in[16], d_in[17],
        d_out);
}

// Round 8
// 192.692 us; speedup vs baseline: 1.5766x; 1.5766x over previous
//
#include <hip/hip_runtime.h>
#include <hip/hip_bf16.h>

typedef unsigned short u16;
typedef unsigned int u32;
typedef __attribute__((ext_vector_type(8))) __bf16 bfrag;   // MFMA A/B fragment (4 VGPRs)
typedef __attribute__((ext_vector_type(4))) float f32x4;    // MFMA C/D fragment

#define NN 30
#define FF 4
#define EE 870
#define BSZ 32
#define CC 64
#define TT 128
#define NF 120
#define TSTRIDE 15240
#define OUTHALF 487680
#define AST 72            // activation LDS row stride in u16
#define NCPB 4            // channels per block
#define NCG  (CC / NCPB)  // channel-groups per bs = 16

// ws layout at +256: u16 weights (B-fragment order, o-major):
//   +0     W2T(msg) | +4096 A1T | +8192 A2T | +12288 V1T | +16384 V2T
//   +20480 A3T 16x64 (rows 4..15 zero) | +21504 V3T 16x64
// at +256+45056: u32 gmask[BSZ*NN]
#define WS_WOFF 256
#define WS_MASKOFF (256 + 45056)

__device__ __forceinline__ float bf2f(u16 u) {
    union { u32 i; float f; } v; v.i = ((u32)u) << 16; return v.f;
}
__device__ __forceinline__ u16 f2bf(float f) {
    __hip_bfloat16 h = __float2bfloat16(f); return *(u16*)&h;
}
__device__ __forceinline__ float ldv(const void* p, int idx, int isbf) {
    if (isbf) return bf2f(((const u16*)p)[idx]);
    return ((const float*)p)[idx];
}
__device__ __forceinline__ float softplus_clip(float z) {
    float sp = fmaxf(z, 0.f) + log1pf(expf(-fabsf(z)));
    return fminf(fmaxf(sp, 1e-8f), 100.f);
}
__device__ __forceinline__ f32x4 MFMA(bfrag a, bfrag b, f32x4 c) {
    return __builtin_amdgcn_mfma_f32_16x16x32_bf16(a, b, c, 0, 0, 0);
}

// Per-wave inline dtype probe. graph entries are exactly 0.0/1.0.
// bf16 layout: even u16 words hit 0x3F80 whp; fp32 layout: even words
// (low mantissa halves of 0.0/1.0) are always 0x0000.
__device__ __forceinline__ int probe_isbf(const u16* g, int lane) {
    int hit = (g[2 * lane] == 0x3F80u) | (g[128 + 2 * lane] == 0x3F80u);
    unsigned long long b = __ballot(hit);
    return (b != 0ull) ? 1 : 0;
}

// ---- prep: transpose weights to B-fragment-friendly o-major bf16; build edge masks
__global__ void prep_ws(const void* __restrict__ mW2,
                        const void* __restrict__ aW1, const void* __restrict__ aW2,
                        const void* __restrict__ vW1, const void* __restrict__ vW2,
                        const void* __restrict__ aW3, const void* __restrict__ vW3,
                        const void* __restrict__ graph,
                        u16* __restrict__ wsW, u32* __restrict__ wsMask) {
    const int lane = threadIdx.x & 63;
    const int isbf = probe_isbf((const u16*)graph, lane);
    const int gtid = blockIdx.x * blockDim.x + threadIdx.x;
    const int gstr = gridDim.x * blockDim.x;
    for (int idx = gtid; idx < 4096; idx += gstr) {
        int k = idx >> 6, o = idx & 63;
        int d = o * 64 + k;
        wsW[d]         = f2bf(ldv(mW2, idx, isbf));
        wsW[4096 + d]  = f2bf(ldv(aW1, idx, isbf));
        wsW[8192 + d]  = f2bf(ldv(aW2, idx, isbf));
        wsW[12288 + d] = f2bf(ldv(vW1, idx, isbf));
        wsW[16384 + d] = f2bf(ldv(vW2, idx, isbf));
    }
    for (int idx = gtid; idx < 1024; idx += gstr) {
        int f = idx >> 6, h = idx & 63;
        wsW[20480 + idx] = (f < 4) ? f2bf(ldv(aW3, h * 4 + f, isbf)) : (u16)0;
        wsW[21504 + idx] = (f < 4) ? f2bf(ldv(vW3, h * 4 + f, isbf)) : (u16)0;
    }
    for (int idx = gtid; idx < BSZ * NN; idx += gstr) {
        int b = idx / NN, i = idx % NN;
        u32 m = 0;
        for (int e = 0; e < 29; e++)
            if (ldv(graph, b * EE + i * 29 + e, isbf) > 0.5f) m |= (1u << e);
        wsMask[idx] = m;
    }
}

__global__ __launch_bounds__(256, 2)
void sim_fused(const void* __restrict__ data,
               const void* __restrict__ graph,
               const void* __restrict__ mW1, const void* __restrict__ mB1,
               const void* __restrict__ mB2,
               const void* __restrict__ aB1, const void* __restrict__ aB2,
               const void* __restrict__ aB3,
               const void* __restrict__ vB1, const void* __restrict__ vB2,
               const void* __restrict__ vB3,
               const u16* __restrict__ wsW, const u32* __restrict__ wsMask,
               void* __restrict__ out)
{
    __shared__ __align__(16) float xN[NF];
    __shared__ __align__(16) float pJ[NN * 64];
    __shared__ __align__(16) u32 gmaskS[32];
    __shared__ __align__(16) u16 S[32 * AST];
    __shared__ __align__(16) u16 Am[32 * AST];  // agg-mean, later h2-mean (alias safe: same wave, prog order)
    __shared__ __align__(16) u16 Av[32 * AST];  // agg-var,  later h2-var
    __shared__ __align__(16) u16 Hm[32 * AST];
    __shared__ __align__(16) u16 Hv[32 * AST];

    const int tid  = threadIdx.x;
    const int lane = tid & 63;
    const int wv   = tid >> 6;        // 0..3
    const int ln15 = lane & 15;
    const int quad = lane >> 4;
    const int bs   = blockIdx.x / NCG;
    const int cg   = blockIdx.x % NCG;
    const int isbf = probe_isbf((const u16*)graph, lane);

    const bool isMean = (wv < 2);
    const int rb = wv & 1;            // this wave's 16-row block

    // ---- channel-invariant setup ----
    if (tid < 32) gmaskS[tid] = (tid < NN) ? wsMask[bs * NN + tid] : 0u;
    if (tid < 128) S[(30 + (tid >> 6)) * AST + (tid & 63)] = 0;  // pad rows stay zero forever

    float w1r[8];
#pragma unroll
    for (int k = 0; k < 8; k++) w1r[k] = ldv(mW1, k * 64 + lane, isbf);
    const float b1r = ldv(mB1, lane, isbf);

    float b2cb[4], h1b[4], h2b[4], b3r[4], ngr[4];
#pragma unroll
    for (int cb = 0; cb < 4; cb++) {
        b2cb[cb] = ldv(mB2, cb * 16 + ln15, isbf);
        h1b[cb]  = ldv(isMean ? aB1 : vB1, cb * 16 + ln15, isbf);
        h2b[cb]  = ldv(isMean ? aB2 : vB2, cb * 16 + ln15, isbf);
    }
#pragma unroll
    for (int r = 0; r < 4; r++) {
        b3r[r] = ldv(isMean ? aB3 : vB3, r, isbf);
        int row = rb * 16 + quad * 4 + r;
        ngr[r] = (row < NN) ? (float)__popc(wsMask[bs * NN + row]) : 0.f;
    }

    const u16* W2T = wsW;
    const u16* H1T = isMean ? (wsW + 4096)  : (wsW + 12288);
    const u16* H2T = isMean ? (wsW + 8192)  : (wsW + 16384);
    const u16* W3T = isMean ? (wsW + 20480) : (wsW + 21504);
    u16* bufA  = isMean ? Am : Av;
    u16* bufH  = isMean ? Hm : Hv;
    u16* bufH2 = isMean ? Am : Av;   // alias of bufA — same-wave program order makes this safe

    // ---- preload B-fragments (step/block-invariant; compiler may sink — known-good r6 form) ----
    bfrag bW2[8], bH1[8], bH2[8];
#pragma unroll
    for (int cb = 0; cb < 4; cb++) {
        bW2[2*cb]   = *(const bfrag*)&W2T[(cb * 16 + ln15) * 64 + quad * 8];
        bW2[2*cb+1] = *(const bfrag*)&W2T[(cb * 16 + ln15) * 64 + 32 + quad * 8];
        bH1[2*cb]   = *(const bfrag*)&H1T[(cb * 16 + ln15) * 64 + quad * 8];
        bH1[2*cb+1] = *(const bfrag*)&H1T[(cb * 16 + ln15) * 64 + 32 + quad * 8];
        bH2[2*cb]   = *(const bfrag*)&H2T[(cb * 16 + ln15) * 64 + quad * 8];
        bH2[2*cb+1] = *(const bfrag*)&H2T[(cb * 16 + ln15) * 64 + 32 + quad * 8];
    }
    const bfrag e_a0 = *(const bfrag*)&W3T[ln15 * 64 + quad * 8];
    const bfrag e_a1 = *(const bfrag*)&W3T[ln15 * 64 + 32 + quad * 8];

    __syncthreads();

    for (int ci = 0; ci < NCPB; ci++) {
        const int c = cg * NCPB + ci;

        // ---- stage this channel's node features ----
        if (isbf) {
            if (tid < 60) {
                u32 w = ((const u32*)data)[((bs * TT + 2 * c) * NF) / 2 + tid];
                xN[tid * 2]     = bf2f((u16)(w & 0xFFFF));
                xN[tid * 2 + 1] = bf2f((u16)(w >> 16));
            }
        } else {
            if (tid < NF) xN[tid] = ((const float*)data)[(bs * TT + 2 * c) * NF + tid];
        }
        __syncthreads();

        for (int step = 0; step < 2; step++) {
            // ---- pJ[j][h] = x_j . W1[4:8, h] ----
            for (int i = wv; i < NN; i += 4) {
                float4 xv = *(const float4*)&xN[i * 4];
                pJ[i * 64 + lane] = xv.x * w1r[4] + xv.y * w1r[5] + xv.z * w1r[6] + xv.w * w1r[7];
            }
            __syncthreads();

            // ---- edge accumulation: S[i][h] = sum_{j active} relu(pI + pJ) ----
            for (int i = wv; i < NN; i += 4) {
                float4 xv = *(const float4*)&xN[i * 4];
                float pI = b1r + xv.x * w1r[0] + xv.y * w1r[1] + xv.z * w1r[2] + xv.w * w1r[3];
                u32 gm = __builtin_amdgcn_readfirstlane(gmaskS[i]);
                float s = 0.f;
#pragma unroll
                for (int e = 0; e < 29; e++) {
                    if (gm & (1u << e)) {          // wave-uniform branch: skips inactive edges
                        int j = e + (e >= i);
                        s += fmaxf(pI + pJ[j * 64 + lane], 0.f);
                    }
                }
                S[i * AST + lane] = f2bf(s);
            }
            __syncthreads();

            // ---- agg = S @ W2 + ng*b2 : each wave does its FULL 16x64 row-block ----
            {
                bfrag a0 = *(const bfrag*)&S[(rb * 16 + ln15) * AST + quad * 8];
                bfrag a1 = *(const bfrag*)&S[(rb * 16 + ln15) * AST + 32 + quad * 8];
#pragma unroll
                for (int cb = 0; cb < 4; cb++) {
                    f32x4 acc = {0.f, 0.f, 0.f, 0.f};
                    acc = MFMA(a0, bW2[2*cb], acc);
                    acc = MFMA(a1, bW2[2*cb+1], acc);
#pragma unroll
                    for (int r = 0; r < 4; r++) {
                        int row = rb * 16 + quad * 4 + r;
                        bufA[row * AST + cb * 16 + ln15] = f2bf(acc[r] + ngr[r] * b2cb[cb]);
                    }
                }
            }

            // ---- h1 = relu(agg @ W1 + b1) — wave-private, no barrier ----
            {
                bfrag a0 = *(const bfrag*)&bufA[(rb * 16 + ln15) * AST + quad * 8];
                bfrag a1 = *(const bfrag*)&bufA[(rb * 16 + ln15) * AST + 32 + quad * 8];
#pragma unroll
                for (int cb = 0; cb < 4; cb++) {
                    f32x4 acc = {0.f, 0.f, 0.f, 0.f};
                    acc = MFMA(a0, bH1[2*cb], acc);
                    acc = MFMA(a1, bH1[2*cb+1], acc);
#pragma unroll
                    for (int r = 0; r < 4; r++) {
                        int row = rb * 16 + quad * 4 + r;
                        bufH[row * AST + cb * 16 + ln15] = f2bf(fmaxf(acc[r] + h1b[cb], 0.f));
                    }
                }
            }

            // ---- h2 = relu(h1 @ W2' + b2') — wave-private, no barrier ----
            {
                bfrag a0 = *(const bfrag*)&bufH[(rb * 16 + ln15) * AST + quad * 8];
                bfrag a1 = *(const bfrag*)&bufH[(rb * 16 + ln15) * AST + 32 + quad * 8];
#pragma unroll
                for (int cb = 0; cb < 4; cb++) {
                    f32x4 acc = {0.f, 0.f, 0.f, 0.f};
                    acc = MFMA(a0, bH2[2*cb], acc);
                    acc = MFMA(a1, bH2[2*cb+1], acc);
#pragma unroll
                    for (int r = 0; r < 4; r++) {
                        int row = rb * 16 + quad * 4 + r;
                        bufH2[row * AST + cb * 16 + ln15] = f2bf(fmaxf(acc[r] + h2b[cb], 0.f));
                    }
                }
            }

            // ---- epilogue: out^T = W3T @ h2^T — wave-private, no barrier ----
            {
                bfrag b0 = *(const bfrag*)&bufH2[(rb * 16 + ln15) * AST + quad * 8];
                bfrag b1 = *(const bfrag*)&bufH2[(rb * 16 + ln15) * AST + 32 + quad * 8];
                f32x4 acc = {0.f, 0.f, 0.f, 0.f};
                acc = MFMA(e_a0, b0, acc);
                acc = MFMA(e_a1, b1, acc);
                const int n = rb * 16 + ln15;
                const int t = 2 * c + step;
                if (quad == 0 && n < NN) {
                    float v[4];
#pragma unroll
                    for (int r = 0; r < 4; r++) v[r] = acc[r] + b3r[r];
                    if (!isMean) {
#pragma unroll
                        for (int r = 0; r < 4; r++) v[r] = softplus_clip(v[r]);
                    }
                    if (t < 127) {
                        size_t o = (size_t)bs * TSTRIDE + (size_t)t * NF + n * 4
                                 + (isMean ? 0 : OUTHALF);
                        if (isbf) {
                            u16* op = (u16*)out;
                            u32 lo = (u32)f2bf(v[0]) | ((u32)f2bf(v[1]) << 16);
                            u32 hi = (u32)f2bf(v[2]) | ((u32)f2bf(v[3]) << 16);
                            *(u32*)&op[o] = lo;
                            *(u32*)&op[o + 2] = hi;
                        } else {
                            float* op = (float*)out;
                            op[o] = v[0]; op[o+1] = v[1]; op[o+2] = v[2]; op[o+3] = v[3];
                        }
                    }
                    if (isMean && step == 0) {
                        xN[n*4]   = v[0]; xN[n*4+1] = v[1];
                        xN[n*4+2] = v[2]; xN[n*4+3] = v[3];
                    }
                }
            }
            __syncthreads();   // xN/pJ/S step boundary
        }
    }
}

extern "C" void kernel_launch(void* const* d_in, const int* in_sizes, int n_in,
                              void* d_out, int out_size, void* d_ws, size_t ws_size,
                              hipStream_t stream) {
    (void)in_sizes; (void)n_in; (void)out_size; (void)ws_size;

    const void* data  = d_in[0];
    const void* graph = d_in[1];
    const void* mW1 = d_in[2];  const void* mB1 = d_in[3];
    const void* mW2 = d_in[4];  const void* mB2 = d_in[5];
    const void* aW1 = d_in[6];  const void* aB1 = d_in[7];
    const void* aW2 = d_in[8];  const void* aB2 = d_in[9];
    const void* aW3 = d_in[10]; const void* aB3 = d_in[11];
    const void* vW1 = d_in[12]; const void* vB1 = d_in[13];
    const void* vW2 = d_in[14]; const void* vB2 = d_in[15];
    const void* vW3 = d_in[16]; const void* vB3 = d_in[17];

    u16* wsW    = (u16*)((char*)d_ws + WS_WOFF);
    u32* wsMask = (u32*)((char*)d_ws + WS_MASKOFF);

    prep_ws<<<8, 256, 0, stream>>>(mW2, aW1, aW2, vW1, vW2, aW3, vW3,
                                   graph, wsW, wsMask);

    sim_fused<<<BSZ * NCG, 256, 0, stream>>>(data, graph,
        mW1, mB1, mB2, aB1, aB2, aB3, vB1, vB2, vB3,
        wsW, wsMask, d_out);
}

// Round 9
// 192.604 us; speedup vs baseline: 1.5773x; 1.0005x over previous
//
#include <hip/hip_runtime.h>
#include <hip/hip_bf16.h>

typedef unsigned short u16;
typedef unsigned int u32;
typedef __attribute__((ext_vector_type(4))) short short4v;  // mfma 16x16x16 A/B frag (2 VGPRs)
typedef __attribute__((ext_vector_type(4))) float f32x4;    // mfma C/D frag

#define NN 30
#define FF 4
#define EE 870
#define BSZ 32
#define CC 64
#define TT 128
#define NF 120
#define TSTRIDE 15240
#define OUTHALF 487680
#define AST 72            // S row stride (u16)
#define WST 68            // LDS weight row stride (u16): breaks o-major bank conflicts
#define NCPB 4
#define NCG  (CC / NCPB)

// ws global layout at +256 (u16, o-major: w[o*64+k] = W[k][o]):
//   +0 W2T | +4096 A1T | +8192 A2T | +12288 V1T | +16384 V2T
//   +20480 A3T 16x64 (rows>=4 zero) | +21504 V3T 16x64
// at +256+45056: u32 gmask[BSZ*NN]
#define WS_WOFF 256
#define WS_MASKOFF (256 + 45056)

__device__ __forceinline__ float bf2f(u16 u) {
    union { u32 i; float f; } v; v.i = ((u32)u) << 16; return v.f;
}
__device__ __forceinline__ u16 f2bf(float f) {
    __hip_bfloat16 h = __float2bfloat16(f); return *(u16*)&h;
}
__device__ __forceinline__ float ldv(const void* p, int idx, int isbf) {
    if (isbf) return bf2f(((const u16*)p)[idx]);
    return ((const float*)p)[idx];
}
__device__ __forceinline__ float softplus_clip(float z) {
    float sp = fmaxf(z, 0.f) + log1pf(expf(-fabsf(z)));
    return fminf(fmaxf(sp, 1e-8f), 100.f);
}
__device__ __forceinline__ f32x4 MFMA16(short4v a, short4v b, f32x4 c) {
    return __builtin_amdgcn_mfma_f32_16x16x16bf16_1k(a, b, c, 0, 0, 0);
}

__device__ __forceinline__ int probe_isbf(const u16* g, int lane) {
    int hit = (g[2 * lane] == 0x3F80u) | (g[128 + 2 * lane] == 0x3F80u);
    unsigned long long b = __ballot(hit);
    return (b != 0ull) ? 1 : 0;
}

// ---- prep: transpose weights to o-major bf16 in ws; build edge masks ----
__global__ void prep_ws(const void* __restrict__ mW2,
                        const void* __restrict__ aW1, const void* __restrict__ aW2,
                        const void* __restrict__ vW1, const void* __restrict__ vW2,
                        const void* __restrict__ aW3, const void* __restrict__ vW3,
                        const void* __restrict__ graph,
                        u16* __restrict__ wsW, u32* __restrict__ wsMask) {
    const int lane = threadIdx.x & 63;
    const int isbf = probe_isbf((const u16*)graph, lane);
    const int gtid = blockIdx.x * blockDim.x + threadIdx.x;
    const int gstr = gridDim.x * blockDim.x;
    for (int idx = gtid; idx < 4096; idx += gstr) {
        int k = idx >> 6, o = idx & 63;
        int d = o * 64 + k;
        wsW[d]         = f2bf(ldv(mW2, idx, isbf));
        wsW[4096 + d]  = f2bf(ldv(aW1, idx, isbf));
        wsW[8192 + d]  = f2bf(ldv(aW2, idx, isbf));
        wsW[12288 + d] = f2bf(ldv(vW1, idx, isbf));
        wsW[16384 + d] = f2bf(ldv(vW2, idx, isbf));
    }
    for (int idx = gtid; idx < 1024; idx += gstr) {
        int f = idx >> 6, h = idx & 63;
        wsW[20480 + idx] = (f < 4) ? f2bf(ldv(aW3, h * 4 + f, isbf)) : (u16)0;
        wsW[21504 + idx] = (f < 4) ? f2bf(ldv(vW3, h * 4 + f, isbf)) : (u16)0;
    }
    for (int idx = gtid; idx < BSZ * NN; idx += gstr) {
        int b = idx / NN, i = idx % NN;
        u32 m = 0;
        for (int e = 0; e < 29; e++)
            if (ldv(graph, b * EE + i * 29 + e, isbf) > 0.5f) m |= (1u << e);
        wsMask[idx] = m;
    }
}

__global__ __launch_bounds__(256, 2)
void sim_fused(const void* __restrict__ data,
               const void* __restrict__ graph,
               const void* __restrict__ mW1, const void* __restrict__ mB1,
               const void* __restrict__ mB2,
               const void* __restrict__ aB1, const void* __restrict__ aB2,
               const void* __restrict__ aB3,
               const void* __restrict__ vB1, const void* __restrict__ vB2,
               const void* __restrict__ vB3,
               const u16* __restrict__ wsW, const u32* __restrict__ wsMask,
               void* __restrict__ out)
{
    __shared__ __align__(16) float xN[NF];
    __shared__ __align__(16) float pJ[NN * 64];
    __shared__ __align__(16) u32 gmaskS[32];
    __shared__ __align__(16) u16 S[32 * AST];
    __shared__ __align__(16) u16 lwM2[64 * WST];   // W2T(msg)
    __shared__ __align__(16) u16 lwH1m[64 * WST];  // A1T
    __shared__ __align__(16) u16 lwH2m[64 * WST];  // A2T
    __shared__ __align__(16) u16 lwH1v[64 * WST];  // V1T
    __shared__ __align__(16) u16 lwH2v[64 * WST];  // V2T
    __shared__ __align__(16) u16 l3m[16 * WST];    // A3T padded
    __shared__ __align__(16) u16 l3v[16 * WST];    // V3T padded
    __shared__ __align__(16) float biasL[5 * 64];  // mB2|aB1|aB2|vB1|vB2

    const int tid  = threadIdx.x;
    const int lane = tid & 63;
    const int wv   = tid >> 6;        // 0..3
    const int ln15 = lane & 15;
    const int quad = lane >> 4;
    const int bs   = blockIdx.x / NCG;
    const int cg   = blockIdx.x % NCG;
    const int isbf = probe_isbf((const u16*)graph, lane);

    const bool isMean = (wv < 2);
    const int nb = wv & 1;            // this wave's 16-node block

    // ---- stage weights global ws -> LDS (restride 64 -> WST) ----
    {
        const u32* w32 = (const u32*)wsW;
        for (int idx = tid; idx < 2048; idx += 256) {   // 64 rows x 32 u32
            int o = idx >> 5, kw = idx & 31;
            int d = o * (WST / 2) + kw;
            ((u32*)lwM2)[d]  = w32[idx];
            ((u32*)lwH1m)[d] = w32[2048 + idx];
            ((u32*)lwH2m)[d] = w32[4096 + idx];
            ((u32*)lwH1v)[d] = w32[6144 + idx];
            ((u32*)lwH2v)[d] = w32[8192 + idx];
        }
        for (int idx = tid; idx < 512; idx += 256) {    // 16 rows x 32 u32
            int o = idx >> 5, kw = idx & 31;
            int d = o * (WST / 2) + kw;
            ((u32*)l3m)[d] = w32[10240 + idx];
            ((u32*)l3v)[d] = w32[10752 + idx];
        }
    }
    if (tid < 64) {
        biasL[tid]       = ldv(mB2, tid, isbf);
        biasL[64 + tid]  = ldv(aB1, tid, isbf);
        biasL[128 + tid] = ldv(aB2, tid, isbf);
        biasL[192 + tid] = ldv(vB1, tid, isbf);
        biasL[256 + tid] = ldv(vB2, tid, isbf);
    }
    if (tid < 32) gmaskS[tid] = (tid < NN) ? wsMask[bs * NN + tid] : 0u;
    if (tid < 128) S[(30 + (tid >> 6)) * AST + (tid & 63)] = 0;  // pad rows stay zero

    float w1r[8];
#pragma unroll
    for (int k = 0; k < 8; k++) w1r[k] = ldv(mW1, k * 64 + lane, isbf);
    const float b1r = ldv(mB1, lane, isbf);
    float b3r[4];
#pragma unroll
    for (int r = 0; r < 4; r++) b3r[r] = ldv(isMean ? aB3 : vB3, r, isbf);

    const u16* wH1 = isMean ? lwH1m : lwH1v;
    const u16* wH2 = isMean ? lwH2m : lwH2v;
    const u16* w3l = isMean ? l3m : l3v;
    const float* bAgg = biasL;
    const float* bH1  = isMean ? (biasL + 64)  : (biasL + 192);
    const float* bH2  = isMean ? (biasL + 128) : (biasL + 256);

    __syncthreads();

    // per-lane node edge count (node = nb*16 + ln15)
    const int myNode = nb * 16 + ln15;
    const float ngp = (myNode < NN) ? (float)__popc(gmaskS[myNode]) : 0.f;

    // transposed-chain layer: D[o_tile fb][node] = sum_kb A(W[kb][fb-cols]) * Bin[kb]
    auto runLayer = [&](const u16* wl, const float* bl, const short4v* Bin,
                        short4v* Bout, float bscale, bool doRelu) {
#pragma unroll
        for (int fb = 0; fb < 4; fb++) {
            f32x4 acc = {0.f, 0.f, 0.f, 0.f};
#pragma unroll
            for (int kb = 0; kb < 4; kb++) {
                short4v a = *(const short4v*)&wl[(fb * 16 + ln15) * WST + kb * 16 + quad * 4];
                acc = MFMA16(a, Bin[kb], acc);
            }
            float4 bv = *(const float4*)&bl[fb * 16 + quad * 4];
            union { short4v v; u16 s[4]; } pk;
#pragma unroll
            for (int r = 0; r < 4; r++) {
                float val = acc[r] + bscale * (&bv.x)[r];
                if (doRelu) val = fmaxf(val, 0.f);
                pk.s[r] = f2bf(val);
            }
            Bout[fb] = pk.v;
        }
    };

    for (int ci = 0; ci < NCPB; ci++) {
        const int c = cg * NCPB + ci;

        // ---- stage this channel's node features ----
        if (isbf) {
            if (tid < 60) {
                u32 w = ((const u32*)data)[((bs * TT + 2 * c) * NF) / 2 + tid];
                xN[tid * 2]     = bf2f((u16)(w & 0xFFFF));
                xN[tid * 2 + 1] = bf2f((u16)(w >> 16));
            }
        } else {
            if (tid < NF) xN[tid] = ((const float*)data)[(bs * TT + 2 * c) * NF + tid];
        }
        __syncthreads();

        for (int step = 0; step < 2; step++) {
            // ---- pJ[j][h] = x_j . W1[4:8, h] ----
            for (int i = wv; i < NN; i += 4) {
                float4 xv = *(const float4*)&xN[i * 4];
                pJ[i * 64 + lane] = xv.x * w1r[4] + xv.y * w1r[5] + xv.z * w1r[6] + xv.w * w1r[7];
            }
            __syncthreads();

            // ---- edge accumulation: S[i][h] = sum_{j active} relu(pI + pJ) ----
            for (int i = wv; i < NN; i += 4) {
                float4 xv = *(const float4*)&xN[i * 4];
                float pI = b1r + xv.x * w1r[0] + xv.y * w1r[1] + xv.z * w1r[2] + xv.w * w1r[3];
                u32 gm = __builtin_amdgcn_readfirstlane(gmaskS[i]);
                float s = 0.f;
#pragma unroll
                for (int e = 0; e < 29; e++) {
                    if (gm & (1u << e)) {
                        int j = e + (e >= i);
                        s += fmaxf(pI + pJ[j * 64 + lane], 0.f);
                    }
                }
                S[i * AST + lane] = f2bf(s);
            }
            __syncthreads();

            // ---- S^T B-fragments: lane holds S[node=nb*16+ln15][k=kb*16+quad*4+j] ----
            short4v Bs[4], Ba[4], Bb[4];
#pragma unroll
            for (int kb = 0; kb < 4; kb++)
                Bs[kb] = *(const short4v*)&S[(nb * 16 + ln15) * AST + kb * 16 + quad * 4];

            // ---- register-chained MLP: agg -> h1 -> h2 (no LDS, no barriers) ----
            runLayer(lwM2, bAgg, Bs, Ba, ngp, false);   // agg = S@W2 + ng*b2
            runLayer(wH1,  bH1,  Ba, Bb, 1.f, true);    // h1 = relu(agg@W1+b1)
            runLayer(wH2,  bH2,  Bb, Ba, 1.f, true);    // h2 = relu(h1@W2+b2)

            // ---- out layer: D = W3T(16x64-padded) @ h2^T ----
            {
                f32x4 acc = {0.f, 0.f, 0.f, 0.f};
#pragma unroll
                for (int kb = 0; kb < 4; kb++) {
                    short4v a = *(const short4v*)&w3l[ln15 * WST + kb * 16 + quad * 4];
                    acc = MFMA16(a, Ba[kb], acc);
                }
                const int n = nb * 16 + ln15;
                const int t = 2 * c + step;
                if (quad == 0 && n < NN) {
                    float v[4];
#pragma unroll
                    for (int r = 0; r < 4; r++) v[r] = acc[r] + b3r[r];
                    if (!isMean) {
#pragma unroll
                        for (int r = 0; r < 4; r++) v[r] = softplus_clip(v[r]);
                    }
                    if (t < 127) {
                        size_t o = (size_t)bs * TSTRIDE + (size_t)t * NF + n * 4
                                 + (isMean ? 0 : OUTHALF);
                        if (isbf) {
                            u16* op = (u16*)out;
                            u32 lo = (u32)f2bf(v[0]) | ((u32)f2bf(v[1]) << 16);
                            u32 hi = (u32)f2bf(v[2]) | ((u32)f2bf(v[3]) << 16);
                            *(u32*)&op[o] = lo;
                            *(u32*)&op[o + 2] = hi;
                        } else {
                            float* op = (float*)out;
                            op[o] = v[0]; op[o+1] = v[1]; op[o+2] = v[2]; op[o+3] = v[3];
                        }
                    }
                    if (isMean && step == 0) {
                        xN[n*4]   = v[0]; xN[n*4+1] = v[1];
                        xN[n*4+2] = v[2]; xN[n*4+3] = v[3];
                    }
                }
            }
            __syncthreads();   // xN/pJ/S step boundary
        }
    }
}

extern "C" void kernel_launch(void* const* d_in, const int* in_sizes, int n_in,
                              void* d_out, int out_size, void* d_ws, size_t ws_size,
                              hipStream_t stream) {
    (void)in_sizes; (void)n_in; (void)out_size; (void)ws_size;

    const void* data  = d_in[0];
    const void* graph = d_in[1];
    const void* mW1 = d_in[2];  const void* mB1 = d_in[3];
    const void* mW2 = d_in[4];  const void* mB2 = d_in[5];
    const void* aW1 = d_in[6];  const void* aB1 = d_in[7];
    const void* aW2 = d_in[8];  const void* aB2 = d_in[9];
    const void* aW3 = d_in[10]; const void* aB3 = d_in[11];
    const void* vW1 = d_in[12]; const void* vB1 = d_in[13];
    const void* vW2 = d_in[14]; const void* vB2 = d_in[15];
    const void* vW3 = d_in[16]; const void* vB3 = d_in[17];

    u16* wsW    = (u16*)((char*)d_ws + WS_WOFF);
    u32* wsMask = (u32*)((char*)d_ws + WS_MASKOFF);

    prep_ws<<<8, 256, 0, stream>>>(mW2, aW1, aW2, vW1, vW2, aW3, vW3,
                                   graph, wsW, wsMask);

    sim_fused<<<BSZ * NCG, 256, 0, stream>>>(data, graph,
        mW1, mB1, mB2, aB1, aB2, aB3, vB1, vB2, vB3,
        wsW, wsMask, d_out);
}

// Round 10
// 156.010 us; speedup vs baseline: 1.9473x; 1.2346x over previous
//
#include <hip/hip_runtime.h>
#include <hip/hip_bf16.h>

typedef unsigned short u16;
typedef unsigned int u32;
typedef __attribute__((ext_vector_type(4))) short short4v;  // mfma 16x16x16 A/B frag (2 VGPRs)
typedef __attribute__((ext_vector_type(4))) float f32x4;    // mfma C/D frag

#define NN 30
#define FF 4
#define EE 870
#define BSZ 32
#define CC 64
#define TT 128
#define NF 120
#define TSTRIDE 15240
#define OUTHALF 487680
#define AST 68            // S row stride (u16): 136 B rows, 8B-aligned frag reads
#define WST 68            // LDS weight row stride (u16)
#define NCPB 2            // channels per SET
#define BPB  16           // blocks per bs: (CC/NCPB)/2 sets

// ws global layout at +256 (u16, o-major: w[o*64+k] = W[k][o]):
//   +0 W2T | +4096 A1T | +8192 A2T | +12288 V1T | +16384 V2T
// at +256+45056: u32 gmask[BSZ*NN]
#define WS_WOFF 256
#define WS_MASKOFF (256 + 45056)

__device__ __forceinline__ float bf2f(u16 u) {
    union { u32 i; float f; } v; v.i = ((u32)u) << 16; return v.f;
}
__device__ __forceinline__ u16 f2bf(float f) {
    __hip_bfloat16 h = __float2bfloat16(f); return *(u16*)&h;
}
__device__ __forceinline__ float ldv(const void* p, int idx, int isbf) {
    if (isbf) return bf2f(((const u16*)p)[idx]);
    return ((const float*)p)[idx];
}
__device__ __forceinline__ float softplus_clip(float z) {
    float sp = fmaxf(z, 0.f) + log1pf(expf(-fabsf(z)));
    return fminf(fmaxf(sp, 1e-8f), 100.f);
}
__device__ __forceinline__ f32x4 MFMA16(short4v a, short4v b, f32x4 c) {
    return __builtin_amdgcn_mfma_f32_16x16x16bf16_1k(a, b, c, 0, 0, 0);
}

__device__ __forceinline__ int probe_isbf(const u16* g, int lane) {
    int hit = (g[2 * lane] == 0x3F80u) | (g[128 + 2 * lane] == 0x3F80u);
    unsigned long long b = __ballot(hit);
    return (b != 0ull) ? 1 : 0;
}

// ---- prep: transpose the five 64x64 weights to o-major bf16; build edge masks ----
__global__ void prep_ws(const void* __restrict__ mW2,
                        const void* __restrict__ aW1, const void* __restrict__ aW2,
                        const void* __restrict__ vW1, const void* __restrict__ vW2,
                        const void* __restrict__ graph,
                        u16* __restrict__ wsW, u32* __restrict__ wsMask) {
    const int lane = threadIdx.x & 63;
    const int isbf = probe_isbf((const u16*)graph, lane);
    const int gtid = blockIdx.x * blockDim.x + threadIdx.x;
    const int gstr = gridDim.x * blockDim.x;
    for (int idx = gtid; idx < 4096; idx += gstr) {
        int k = idx >> 6, o = idx & 63;
        int d = o * 64 + k;
        wsW[d]         = f2bf(ldv(mW2, idx, isbf));
        wsW[4096 + d]  = f2bf(ldv(aW1, idx, isbf));
        wsW[8192 + d]  = f2bf(ldv(aW2, idx, isbf));
        wsW[12288 + d] = f2bf(ldv(vW1, idx, isbf));
        wsW[16384 + d] = f2bf(ldv(vW2, idx, isbf));
    }
    for (int idx = gtid; idx < BSZ * NN; idx += gstr) {
        int b = idx / NN, i = idx % NN;
        u32 m = 0;
        for (int e = 0; e < 29; e++)
            if (ldv(graph, b * EE + i * 29 + e, isbf) > 0.5f) m |= (1u << e);
        wsMask[idx] = m;
    }
}

__global__ __launch_bounds__(512, 4)
void sim_fused(const void* __restrict__ data,
               const void* __restrict__ graph,
               const void* __restrict__ mW1, const void* __restrict__ mB1,
               const void* __restrict__ mB2,
               const void* __restrict__ aB1, const void* __restrict__ aB2,
               const void* __restrict__ aB3,
               const void* __restrict__ vB1, const void* __restrict__ vB2,
               const void* __restrict__ vB3,
               const void* __restrict__ aW3, const void* __restrict__ vW3,
               const u16* __restrict__ wsW, const u32* __restrict__ wsMask,
               void* __restrict__ out)
{
    // two independent channel-sets share one weight copy
    __shared__ __align__(16) float xN[2][NF];
    __shared__ __align__(16) u16 pJs[2][NN * 64];
    __shared__ __align__(16) u32 gmaskS[32];
    __shared__ __align__(16) u16 S[2][32 * AST];
    __shared__ __align__(16) u16 lwM2[64 * WST];
    __shared__ __align__(16) u16 lwH1m[64 * WST];
    __shared__ __align__(16) u16 lwH2m[64 * WST];
    __shared__ __align__(16) u16 lwH1v[64 * WST];
    __shared__ __align__(16) u16 lwH2v[64 * WST];
    __shared__ __align__(16) float biasL[5 * 64];  // mB2|aB1|aB2|vB1|vB2

    const int tid  = threadIdx.x;
    const int lane = tid & 63;
    const int wv   = tid >> 6;        // 0..7
    const int set  = wv >> 2;         // 0..1 : channel-set
    const int swv  = wv & 3;          // 0..3 within set
    const int ln15 = lane & 15;
    const int quad = lane >> 4;
    const int bs   = blockIdx.x / BPB;
    const int bg   = blockIdx.x % BPB;
    const int cg   = bg * 2 + set;    // channel group 0..31 (NCPB channels each)
    const int isbf = probe_isbf((const u16*)graph, lane);

    const bool isMean = (swv < 2);
    const int nb = swv & 1;           // this wave's 16-node block

    // ---- stage weights global ws -> LDS (restride 64 -> WST), 512 threads ----
    {
        const u32* w32 = (const u32*)wsW;
        for (int idx = tid; idx < 2048; idx += 512) {   // 64 rows x 32 u32
            int o = idx >> 5, kw = idx & 31;
            int d = o * (WST / 2) + kw;
            ((u32*)lwM2)[d]  = w32[idx];
            ((u32*)lwH1m)[d] = w32[2048 + idx];
            ((u32*)lwH2m)[d] = w32[4096 + idx];
            ((u32*)lwH1v)[d] = w32[6144 + idx];
            ((u32*)lwH2v)[d] = w32[8192 + idx];
        }
    }
    if (tid < 64) {
        biasL[tid]       = ldv(mB2, tid, isbf);
        biasL[64 + tid]  = ldv(aB1, tid, isbf);
        biasL[128 + tid] = ldv(aB2, tid, isbf);
        biasL[192 + tid] = ldv(vB1, tid, isbf);
        biasL[256 + tid] = ldv(vB2, tid, isbf);
    }
    if (tid < 32) gmaskS[tid] = (tid < NN) ? wsMask[bs * NN + tid] : 0u;
    if (tid < 256) {  // zero pad rows 30,31 of both sets' S (stay zero forever)
        int s2 = tid >> 7, row = 30 + ((tid >> 6) & 1);
        S[s2][row * AST + (tid & 63)] = 0;
    }

    float w1r[8];
#pragma unroll
    for (int k = 0; k < 8; k++) w1r[k] = ldv(mW1, k * 64 + lane, isbf);
    const float b1r = ldv(mB1, lane, isbf);
    float b3r[4];
#pragma unroll
    for (int r = 0; r < 4; r++) b3r[r] = ldv(isMean ? aB3 : vB3, r, isbf);

    const u16* wH1 = isMean ? lwH1m : lwH1v;
    const u16* wH2 = isMean ? lwH2m : lwH2v;
    const float* bAgg = biasL;
    const float* bH1  = isMean ? (biasL + 64)  : (biasL + 192);
    const float* bH2  = isMean ? (biasL + 128) : (biasL + 256);

    // ---- W3^T A-fragments in registers (16x64 padded; rows>=4 zero) ----
    // A[m=ln15][k=kb*16+quad*4+j] = (m<4) ? W3[k][m] : 0. Gather = non-remat => stays resident.
    const void* W3src = isMean ? aW3 : vW3;
    short4v eA[4];
#pragma unroll
    for (int kb = 0; kb < 4; kb++) {
        union { short4v v; u16 s[4]; } pk;
#pragma unroll
        for (int j = 0; j < 4; j++) {
            int k = kb * 16 + quad * 4 + j;
            pk.s[j] = (ln15 < 4)
                ? (isbf ? ((const u16*)W3src)[k * 4 + ln15]
                        : f2bf(((const float*)W3src)[k * 4 + ln15]))
                : (u16)0;
        }
        eA[kb] = pk.v;
    }

    __syncthreads();

    const int myNode = nb * 16 + ln15;
    const float ngp = (myNode < NN) ? (float)__popc(gmaskS[myNode]) : 0.f;

    // transposed-chain layer: register B-frag in, register B-frag out
    auto runLayer = [&](const u16* wl, const float* bl, const short4v* Bin,
                        short4v* Bout, float bscale, bool doRelu) {
#pragma unroll
        for (int fb = 0; fb < 4; fb++) {
            f32x4 acc = {0.f, 0.f, 0.f, 0.f};
#pragma unroll
            for (int kb = 0; kb < 4; kb++) {
                short4v a = *(const short4v*)&wl[(fb * 16 + ln15) * WST + kb * 16 + quad * 4];
                acc = MFMA16(a, Bin[kb], acc);
            }
            float4 bv = *(const float4*)&bl[fb * 16 + quad * 4];
            union { short4v v; u16 s[4]; } pk;
#pragma unroll
            for (int r = 0; r < 4; r++) {
                float val = acc[r] + bscale * (&bv.x)[r];
                if (doRelu) val = fmaxf(val, 0.f);
                pk.s[r] = f2bf(val);
            }
            Bout[fb] = pk.v;
        }
    };

    const int setTid = tid & 255;

    for (int ci = 0; ci < NCPB; ci++) {
        const int c = cg * NCPB + ci;

        // ---- stage this set's channel features ----
        if (isbf) {
            if (setTid < 60) {
                u32 w = ((const u32*)data)[((bs * TT + 2 * c) * NF) / 2 + setTid];
                xN[set][setTid * 2]     = bf2f((u16)(w & 0xFFFF));
                xN[set][setTid * 2 + 1] = bf2f((u16)(w >> 16));
            }
        } else {
            if (setTid < NF) xN[set][setTid] = ((const float*)data)[(bs * TT + 2 * c) * NF + setTid];
        }
        __syncthreads();

        for (int step = 0; step < 2; step++) {
            // ---- pJ[j][h] = x_j . W1[4:8, h]  (bf16 in LDS) ----
            for (int i = swv; i < NN; i += 4) {
                float4 xv = *(const float4*)&xN[set][i * 4];
                pJs[set][i * 64 + lane] =
                    f2bf(xv.x * w1r[4] + xv.y * w1r[5] + xv.z * w1r[6] + xv.w * w1r[7]);
            }
            __syncthreads();

            // ---- edge accumulation: S[i][h] = sum_{j active} relu(pI + pJ) ----
            for (int i = swv; i < NN; i += 4) {
                float4 xv = *(const float4*)&xN[set][i * 4];
                float pI = b1r + xv.x * w1r[0] + xv.y * w1r[1] + xv.z * w1r[2] + xv.w * w1r[3];
                u32 gm = __builtin_amdgcn_readfirstlane(gmaskS[i]);
                float s = 0.f;
#pragma unroll
                for (int e = 0; e < 29; e++) {
                    if (gm & (1u << e)) {
                        int j = e + (e >= i);
                        s += fmaxf(pI + bf2f(pJs[set][j * 64 + lane]), 0.f);
                    }
                }
                S[set][i * AST + lane] = f2bf(s);
            }
            __syncthreads();

            // ---- S^T B-fragments ----
            short4v Bs[4], Ba[4], Bb[4];
#pragma unroll
            for (int kb = 0; kb < 4; kb++)
                Bs[kb] = *(const short4v*)&S[set][(nb * 16 + ln15) * AST + kb * 16 + quad * 4];

            // ---- register-chained MLP: agg -> h1 -> h2 (no LDS round-trips) ----
            runLayer(lwM2, bAgg, Bs, Ba, ngp, false);   // agg = S@W2 + ng*b2
            runLayer(wH1,  bH1,  Ba, Bb, 1.f, true);    // h1 = relu(agg@W1+b1)
            runLayer(wH2,  bH2,  Bb, Ba, 1.f, true);    // h2 = relu(h1@W2+b2)

            // ---- out layer: D = W3T(reg) @ h2^T ----
            {
                f32x4 acc = {0.f, 0.f, 0.f, 0.f};
#pragma unroll
                for (int kb = 0; kb < 4; kb++) acc = MFMA16(eA[kb], Ba[kb], acc);
                const int n = nb * 16 + ln15;
                const int t = 2 * c + step;
                if (quad == 0 && n < NN) {
                    float v[4];
#pragma unroll
                    for (int r = 0; r < 4; r++) v[r] = acc[r] + b3r[r];
                    if (!isMean) {
#pragma unroll
                        for (int r = 0; r < 4; r++) v[r] = softplus_clip(v[r]);
                    }
                    if (t < 127) {
                        size_t o = (size_t)bs * TSTRIDE + (size_t)t * NF + n * 4
                                 + (isMean ? 0 : OUTHALF);
                        if (isbf) {
                            u16* op = (u16*)out;
                            u32 lo = (u32)f2bf(v[0]) | ((u32)f2bf(v[1]) << 16);
                            u32 hi = (u32)f2bf(v[2]) | ((u32)f2bf(v[3]) << 16);
                            *(u32*)&op[o] = lo;
                            *(u32*)&op[o + 2] = hi;
                        } else {
                            float* op = (float*)out;
                            op[o] = v[0]; op[o+1] = v[1]; op[o+2] = v[2]; op[o+3] = v[3];
                        }
                    }
                    if (isMean && step == 0) {
                        xN[set][n*4]   = v[0]; xN[set][n*4+1] = v[1];
                        xN[set][n*4+2] = v[2]; xN[set][n*4+3] = v[3];
                    }
                }
            }
            __syncthreads();   // xN/pJ/S step boundary
        }
    }
}

extern "C" void kernel_launch(void* const* d_in, const int* in_sizes, int n_in,
                              void* d_out, int out_size, void* d_ws, size_t ws_size,
                              hipStream_t stream) {
    (void)in_sizes; (void)n_in; (void)out_size; (void)ws_size;

    const void* data  = d_in[0];
    const void* graph = d_in[1];
    const void* mW1 = d_in[2];  const void* mB1 = d_in[3];
    const void* mW2 = d_in[4];  const void* mB2 = d_in[5];
    const void* aW1 = d_in[6];  const void* aB1 = d_in[7];
    const void* aW2 = d_in[8];  const void* aB2 = d_in[9];
    const void* aW3 = d_in[10]; const void* aB3 = d_in[11];
    const void* vW1 = d_in[12]; const void* vB1 = d_in[13];
    const void* vW2 = d_in[14]; const void* vB2 = d_in[15];
    const void* vW3 = d_in[16]; const void* vB3 = d_in[17];

    u16* wsW    = (u16*)((char*)d_ws + WS_WOFF);
    u32* wsMask = (u32*)((char*)d_ws + WS_MASKOFF);

    prep_ws<<<8, 256, 0, stream>>>(mW2, aW1, aW2, vW1, vW2,
                                   graph, wsW, wsMask);

    sim_fused<<<BSZ * BPB, 512, 0, stream>>>(data, graph,
        mW1, mB1, mB2, aB1, aB2, aB3, vB1, vB2, vB3,
        aW3, vW3, wsW, wsMask, d_out);
}